// Round 9
// baseline (245.656 us; speedup 1.0000x reference)
//
#include <hip/hip_runtime.h>
#include <stdint.h>

typedef unsigned short u16;
typedef __attribute__((ext_vector_type(4))) float f32x4;
typedef __attribute__((ext_vector_type(2))) __bf16 bf16x2;
typedef __attribute__((ext_vector_type(8))) __bf16 bf16x8;
typedef __attribute__((ext_vector_type(4))) u16 u16x4;
typedef __attribute__((ext_vector_type(2))) __fp16 h16x2;
typedef __attribute__((ext_vector_type(8))) __fp16 h16x8;

#define AS1 __attribute__((address_space(1)))
#define AS3 __attribute__((address_space(3)))
#define GLOAD_LDS16(gp, lp) \
  __builtin_amdgcn_global_load_lds((const AS1 void*)(gp), (AS3 void*)(lp), 16, 0, 0)

__device__ __forceinline__ u16 f2bf(float f) {
  union { float f; unsigned u; } v; v.f = f;
  return (u16)((v.u + 0x7FFFu + ((v.u >> 16) & 1u)) >> 16);
}
__device__ __forceinline__ u16 f2h(float f) {
  union { _Float16 h; u16 u; } v; v.h = (_Float16)f; return v.u;
}
__device__ __forceinline__ float bf2f(u16 u) {
  union { unsigned u; float f; } v; v.u = ((unsigned)u) << 16; return v.f;
}
__device__ __forceinline__ float fexp2(float x) {
#if __has_builtin(__builtin_amdgcn_exp2f)
  return __builtin_amdgcn_exp2f(x);
#else
  return exp2f(x);
#endif
}
__device__ __forceinline__ h16x2 pkh(float a, float b) {
  return __builtin_amdgcn_cvt_pkrtz(a, b);
}
__device__ __forceinline__ u16x4 pack4(float a, float b, float c, float d) {
#if __has_builtin(__builtin_amdgcn_cvt_pk_bf16_f32)
  union { struct { bf16x2 lo, hi; } p; u16x4 v; } u;
  u.p.lo = __builtin_amdgcn_cvt_pk_bf16_f32(a, b);
  u.p.hi = __builtin_amdgcn_cvt_pk_bf16_f32(c, d);
  return u.v;
#else
  u16x4 r; r.x = f2bf(a); r.y = f2bf(b); r.z = f2bf(c); r.w = f2bf(d); return r;
#endif
}

#define LOG2E 1.44269504f

// ---------- fp32 -> bf16 conversion ----------
__global__ __launch_bounds__(256) void convert_all(
    const float* __restrict__ x, const float* __restrict__ y,
    const float* __restrict__ wq, const float* __restrict__ wk,
    const float* __restrict__ wv, const float* __restrict__ wo,
    const float* __restrict__ mask,
    u16* __restrict__ xb, u16* __restrict__ yb, u16* __restrict__ wqb,
    u16* __restrict__ wkb, u16* __restrict__ wvb, u16* __restrict__ wob,
    u16* __restrict__ maskb) {
  size_t i = (size_t)blockIdx.x * 256 + threadIdx.x;  // float4 index, 4M total
  const float* src; u16* dst; float scale = 1.0f; size_t off;
  if (i < (size_t)(1u << 20)) { src = x; dst = xb; off = i; }
  else if (i < (size_t)(2u << 20)) { src = y; dst = yb; off = i - (1u << 20); }
  else if (i < (size_t)(3u << 20)) {
    size_t j = i - (size_t)(2u << 20);
    unsigned w = (unsigned)(j >> 18); off = j & ((1u << 18) - 1);
    if (w == 0)      { src = wq; dst = wqb; scale = 0.125f * LOG2E; }
    else if (w == 1) { src = wk; dst = wkb; }
    else if (w == 2) { src = wv; dst = wvb; }
    else             { src = wo; dst = wob; }
  } else { src = mask; dst = maskb; scale = LOG2E; off = i - (size_t)(3u << 20); }
  f32x4 v = ((const f32x4*)src)[off];
  ((u16x4*)dst)[off] = pack4(v.x * scale, v.y * scale, v.z * scale, v.w * scale);
}

// ---------- BT-GEMM core: 128x128 tile, K=1024, BK=64, XOR-swizzled ----------
__device__ __forceinline__ void gemm_core64(
    const u16* __restrict__ A, const u16* __restrict__ Bt, int tm, int tn,
    u16* As, u16* Bs, f32x4 acc[4][4], int wave, int lane) {
  constexpr int K = 1024;
  const int l15 = lane & 15, quad = lane >> 4;
  const int wr = wave >> 1, wc = wave & 1;
  const int srow = lane >> 3;
  const int scol = ((lane & 7) ^ (srow & 7)) * 8;
  const u16* Ag = A + (size_t)(tm + wave * 32 + srow) * K + scol;
  const u16* Bg = Bt + (size_t)(tn + wave * 32 + srow) * K + scol;
  const int rsw = l15 & 7;

  for (int k0 = 0; k0 < K; k0 += 64) {
    __syncthreads();
#pragma unroll
    for (int c = 0; c < 4; ++c)
      GLOAD_LDS16(Ag + (size_t)c * 8 * K + k0, &As[(wave * 4 + c) * 512]);
#pragma unroll
    for (int c = 0; c < 4; ++c)
      GLOAD_LDS16(Bg + (size_t)c * 8 * K + k0, &Bs[(wave * 4 + c) * 512]);
    __syncthreads();
#pragma unroll
    for (int kq = 0; kq < 2; ++kq) {
      bf16x8 af[4], bfr[4];
#pragma unroll
      for (int mi = 0; mi < 4; ++mi)
        af[mi] = *(const bf16x8*)&As[(wr * 64 + mi * 16 + l15) * 64 +
                                     ((kq * 4 + quad) ^ rsw) * 8];
#pragma unroll
      for (int ni = 0; ni < 4; ++ni)
        bfr[ni] = *(const bf16x8*)&Bs[(wc * 64 + ni * 16 + l15) * 64 +
                                      ((kq * 4 + quad) ^ rsw) * 8];
#pragma unroll
      for (int mi = 0; mi < 4; ++mi)
#pragma unroll
        for (int ni = 0; ni < 4; ++ni)
          acc[mi][ni] = __builtin_amdgcn_mfma_f32_16x16x32_bf16(
              af[mi], bfr[ni], acc[mi][ni], 0, 0, 0);
    }
  }
}

// ---------- fused Q/K/Vt projections (Vt written as f16) ----------
__global__ __launch_bounds__(256, 3) void qkv_gemm(
    const u16* __restrict__ xb, const u16* __restrict__ yb,
    const u16* __restrict__ wqb, const u16* __restrict__ wkb,
    const u16* __restrict__ wvb,
    u16* __restrict__ Qw, u16* __restrict__ Kw, u16* __restrict__ Vtw) {
  __shared__ __align__(16) u16 As[128 * 64];
  __shared__ __align__(16) u16 Bs[128 * 64];
  const int tid = threadIdx.x, wave = tid >> 6, lane = tid & 63;
  const int l15 = lane & 15, quad = lane >> 4;
  const int wr = wave >> 1, wc = wave & 1;
  const int z = blockIdx.z;
  const u16 *A, *Bt; int tm, tn;
  if (z == 0)      { A = yb;  Bt = wqb; tm = blockIdx.y * 128; tn = blockIdx.x * 128; }
  else if (z == 1) { A = xb;  Bt = wkb; tm = blockIdx.y * 128; tn = blockIdx.x * 128; }
  else             { A = wvb; Bt = xb;  tm = blockIdx.x * 128; tn = blockIdx.y * 128; }

  f32x4 acc[4][4] = {};
  gemm_core64(A, Bt, tm, tn, As, Bs, acc, wave, lane);

#pragma unroll
  for (int mi = 0; mi < 4; ++mi) {
#pragma unroll
    for (int ni = 0; ni < 4; ++ni) {
#pragma unroll
      for (int r = 0; r < 4; ++r) {
        int gm = tm + wr * 64 + mi * 16 + quad * 4 + r;
        int gn = tn + wc * 64 + ni * 16 + l15;
        float val = acc[mi][ni][r];
        if (z == 2) {  // Vt: [B][H][64][S]  f16
          int h = gm >> 6, dh = gm & 63, b = gn >> 11, s = gn & 2047;
          Vtw[(((size_t)(b * 16 + h) * 64 + dh) << 11) + s] = f2h(val);
        } else {       // Q/K: [B][H][S][64]  bf16
          int b = gm >> 11, s = gm & 2047, h = gn >> 6, dh = gn & 63;
          u16* dst = (z == 0) ? Qw : Kw;
          dst[(((size_t)(b * 16 + h) * 2048 + s) << 6) + dh] = f2bf(val);
        }
      }
    }
  }
}

// ---------- output projection: 64x128 tiles (512 blocks) ----------
__global__ __launch_bounds__(256, 3) void out_gemm(
    const u16* __restrict__ Ow, const u16* __restrict__ wob,
    float* __restrict__ C) {
  constexpr int K = 1024;
  __shared__ __align__(16) u16 As[64 * 64];
  __shared__ __align__(16) u16 Bs[128 * 64];
  const int tid = threadIdx.x, wave = tid >> 6, lane = tid & 63;
  const int l15 = lane & 15, quad = lane >> 4;
  const int wr = wave >> 1, wc = wave & 1;
  const int tm = blockIdx.y * 64, tn = blockIdx.x * 128;
  const int srow = lane >> 3;
  const int scol = ((lane & 7) ^ (srow & 7)) * 8;
  const u16* Ag = Ow + (size_t)(tm + wave * 16 + srow) * K + scol;
  const u16* Bg = wob + (size_t)(tn + wave * 32 + srow) * K + scol;
  const int rsw = l15 & 7;

  f32x4 acc[2][4] = {};
  for (int k0 = 0; k0 < K; k0 += 64) {
    __syncthreads();
#pragma unroll
    for (int c = 0; c < 2; ++c)
      GLOAD_LDS16(Ag + (size_t)c * 8 * K + k0, &As[(wave * 2 + c) * 512]);
#pragma unroll
    for (int c = 0; c < 4; ++c)
      GLOAD_LDS16(Bg + (size_t)c * 8 * K + k0, &Bs[(wave * 4 + c) * 512]);
    __syncthreads();
#pragma unroll
    for (int kq = 0; kq < 2; ++kq) {
      bf16x8 af[2], bfr[4];
#pragma unroll
      for (int mi = 0; mi < 2; ++mi)
        af[mi] = *(const bf16x8*)&As[(wr * 32 + mi * 16 + l15) * 64 +
                                     ((kq * 4 + quad) ^ rsw) * 8];
#pragma unroll
      for (int ni = 0; ni < 4; ++ni)
        bfr[ni] = *(const bf16x8*)&Bs[(wc * 64 + ni * 16 + l15) * 64 +
                                      ((kq * 4 + quad) ^ rsw) * 8];
#pragma unroll
      for (int mi = 0; mi < 2; ++mi)
#pragma unroll
        for (int ni = 0; ni < 4; ++ni)
          acc[mi][ni] = __builtin_amdgcn_mfma_f32_16x16x32_bf16(
              af[mi], bfr[ni], acc[mi][ni], 0, 0, 0);
    }
  }

#pragma unroll
  for (int mi = 0; mi < 2; ++mi)
#pragma unroll
    for (int ni = 0; ni < 4; ++ni)
#pragma unroll
      for (int r = 0; r < 4; ++r) {
        int gm = tm + wr * 32 + mi * 16 + quad * 4 + r;
        int gn = tn + wc * 64 + ni * 16 + l15;
        C[(size_t)gm * 1024 + gn] = acc[mi][ni][r];
      }
}

// ---------- attention v9: ksplit=2 (4 waves/SIMD) + full-rate K32-f16 PV ----------
// grid (qt=16, h=16, z=4), z = b*2+ks; block: 128 q x 1024 keys, 8 iters of 128.
// QK subtile s maps A-row i -> key (i>>2)*8 + s*4 + (i&3); after s=0,1 a lane's
// S-frags concatenate into the 16x16x32_f16 A-operand (k=quad*8+j, j=s*4+r).
// K store swizzle: slot = blk ^ ((key&3)|((key>>1)&4))  (read X spans 8 groups).
// Outputs: f32 partials Op[ks] [B][S][1024] + den [ks][B][H][S]; combine kernel.
__global__ __launch_bounds__(256, 4) void attn_kernel(
    const u16* __restrict__ Qw, const u16* __restrict__ Kw,
    const u16* __restrict__ Vtw, const u16* __restrict__ maskb,
    float* __restrict__ Op0, float* __restrict__ Op1, float* __restrict__ denb) {
  constexpr int S = 2048;
  __shared__ __align__(16) u16 Ks[128 * 64];  // bf16 [key][dh], swizzled (see above)
  __shared__ __align__(16) u16 Vs[64 * 128];  // f16  [dh][key]; blk c at slot c^(dh&15)
  const int tid = threadIdx.x;
  const int wave = tid >> 6, lane = tid & 63;
  const int l15 = lane & 15, quad = lane >> 4;
  const int qt = blockIdx.x, h = blockIdx.y, z = blockIdx.z;
  const int b = z >> 1, ks = z & 1;
  const size_t head = ((size_t)(b * 16 + h)) * S * 64;
  const int kbase = ks * 1024;
  const int qbase = qt * 128 + wave * 32;  // wave owns 32 q-rows

  // Q B-frags: B[n=q=l15][k=quad*8+j]; Qw pre-scaled by log2e/8
  bf16x8 qf[2][2];
#pragma unroll
  for (int q2 = 0; q2 < 2; ++q2)
#pragma unroll
    for (int kq = 0; kq < 2; ++kq)
      qf[q2][kq] = *(const bf16x8*)&Qw[head +
          (size_t)(qbase + q2 * 16 + l15) * 64 + kq * 32 + quad * 8];

  const __fp16 one_h = (__fp16)1.0f;
  const h16x8 ones = {one_h, one_h, one_h, one_h, one_h, one_h, one_h, one_h};

  f32x4 oa[2][4] = {};
  f32x4 den[2] = {};

  // K staging: chunk g = keys g*8..+7; lane: key = g*8 + (l>>3);
  // slot l&7 <- global blk (l&7) ^ swz(key), swz(key) = (key&3)|((key>>1)&4)
  const int k_r = lane >> 3;                 // key&7 = k_r
  // V staging: chunk g = dh g*4..+3; lane: dh = g*4 + (l>>4); slot l&15 <- blk (l&15)^(dh&15)
  const int v_r = lane >> 4;
  const int v_cl = lane & 15;
  // QK read swizzle component (independent of s): (l15&3)|(((l15>>2)&1)<<2)
  const int rswz = (l15 & 3) | (((l15 >> 2) & 1) << 2);

  for (int kt = 0; kt < 1024; kt += 128) {
    __syncthreads();
#pragma unroll
    for (int c = 0; c < 4; ++c) {
      int g = wave * 4 + c;
      int swz = (k_r & 3) | ((g & 1) << 2);          // swz of key = g*8+k_r
      int k_c = ((lane & 7) ^ swz) * 8;
      GLOAD_LDS16(&Kw[head + (size_t)(kbase + kt + g * 8 + k_r) * 64 + k_c],
                  &Ks[g * 512]);
    }
#pragma unroll
    for (int c = 0; c < 4; ++c) {
      int g = wave * 4 + c;
      int dh = g * 4 + v_r;
      GLOAD_LDS16(&Vtw[head + (size_t)dh * S + kbase + kt + ((v_cl ^ (dh & 15)) * 8)],
                  &Vs[g * 512]);
    }
    // mask loads (bf16, log2e-scaled), permuted-key order: col t*32+quad*8+s*4
    u16x4 mq[2][4][2];
#pragma unroll
    for (int q2 = 0; q2 < 2; ++q2)
#pragma unroll
      for (int t = 0; t < 4; ++t)
#pragma unroll
        for (int s = 0; s < 2; ++s)
          mq[q2][t][s] = *(const u16x4*)&maskb[(size_t)(qbase + q2 * 16 + l15) * S +
                                               kbase + kt + t * 32 + quad * 8 + s * 4];
    __syncthreads();

#pragma unroll
    for (int t = 0; t < 4; ++t) {
      // S^T subtiles s=0,1 with permuted key rows
      f32x4 sa[2][2] = {};  // [s][q2]
#pragma unroll
      for (int s = 0; s < 2; ++s) {
        int krow = t * 32 + ((l15 >> 2) << 3) + s * 4 + (l15 & 3);
#pragma unroll
        for (int kq = 0; kq < 2; ++kq) {
          bf16x8 ak = *(const bf16x8*)&Ks[krow * 64 + ((kq * 4 + quad) ^ rswz) * 8];
          sa[s][0] = __builtin_amdgcn_mfma_f32_16x16x32_bf16(ak, qf[0][kq], sa[s][0], 0, 0, 0);
          sa[s][1] = __builtin_amdgcn_mfma_f32_16x16x32_bf16(ak, qf[1][kq], sa[s][1], 0, 0, 0);
        }
      }
      // P = exp2(S+mask) packed as 16x16x32_f16 A-operand: j = s*4+r
      h16x8 pf[2];
#pragma unroll
      for (int q2 = 0; q2 < 2; ++q2) {
        union { h16x2 p[4]; h16x8 v; } u;
#pragma unroll
        for (int s = 0; s < 2; ++s) {
          float e0 = fexp2(sa[s][q2][0] + bf2f(mq[q2][t][s].x));
          float e1 = fexp2(sa[s][q2][1] + bf2f(mq[q2][t][s].y));
          float e2 = fexp2(sa[s][q2][2] + bf2f(mq[q2][t][s].z));
          float e3 = fexp2(sa[s][q2][3] + bf2f(mq[q2][t][s].w));
          u.p[s * 2 + 0] = pkh(e0, e1);
          u.p[s * 2 + 1] = pkh(e2, e3);
        }
        pf[q2] = u.v;
      }
      // O += P·V ; den += P·1   (full-rate K=32 f16 MFMA)
#pragma unroll
      for (int nv = 0; nv < 4; ++nv) {
        h16x8 bv = *(const h16x8*)&Vs[(nv * 16 + l15) * 128 +
                                      (((t * 4 + quad) ^ l15) * 8)];
        oa[0][nv] = __builtin_amdgcn_mfma_f32_16x16x32_f16(pf[0], bv, oa[0][nv], 0, 0, 0);
        oa[1][nv] = __builtin_amdgcn_mfma_f32_16x16x32_f16(pf[1], bv, oa[1][nv], 0, 0, 0);
      }
      den[0] = __builtin_amdgcn_mfma_f32_16x16x32_f16(pf[0], ones, den[0], 0, 0, 0);
      den[1] = __builtin_amdgcn_mfma_f32_16x16x32_f16(pf[1], ones, den[1], 0, 0, 0);
    }
  }

  // epilogue: f32 partials; C-layout row q = quad*4+r, col dh = nv*16+l15
  float* Op = ks ? Op1 : Op0;
#pragma unroll
  for (int q2 = 0; q2 < 2; ++q2) {
#pragma unroll
    for (int nv = 0; nv < 4; ++nv) {
#pragma unroll
      for (int r = 0; r < 4; ++r) {
        int q = qbase + q2 * 16 + quad * 4 + r;
        int dh = nv * 16 + l15;
        Op[((size_t)(b * S + q) << 10) + h * 64 + dh] = oa[q2][nv][r];
      }
    }
  }
  if (l15 == 0) {
#pragma unroll
    for (int q2 = 0; q2 < 2; ++q2)
#pragma unroll
      for (int r = 0; r < 4; ++r) {
        int q = qbase + q2 * 16 + quad * 4 + r;
        denb[((size_t)(ks * 2 + b) * 16 + h) * 2048 + q] = den[q2][r];
      }
  }
}

// ---------- combine partials -> Ow bf16 ----------
__global__ __launch_bounds__(256) void combine(
    const float* __restrict__ Op0, const float* __restrict__ Op1,
    const float* __restrict__ denb, u16* __restrict__ Ow) {
  size_t i = (size_t)blockIdx.x * 256 + threadIdx.x;  // f32x4 idx over 1M
  size_t flat = i * 4;
  int c = (int)(flat & 1023), h = c >> 6;
  int s = (int)((flat >> 10) & 2047);
  int b = (int)(flat >> 21);
  f32x4 a = ((const f32x4*)Op0)[i];
  f32x4 d = ((const f32x4*)Op1)[i];
  float dn = denb[((size_t)b * 16 + h) * 2048 + s] +
             denb[((size_t)(2 + b) * 16 + h) * 2048 + s] + 1e-10f;
  float r = 1.0f / dn;
  ((u16x4*)Ow)[i] = pack4((a.x + d.x) * r, (a.y + d.y) * r,
                          (a.z + d.z) * r, (a.w + d.w) * r);
}

extern "C" void kernel_launch(void* const* d_in, const int* in_sizes, int n_in,
                              void* d_out, int out_size, void* d_ws, size_t ws_size,
                              hipStream_t stream) {
  const float* x    = (const float*)d_in[0];
  const float* y    = (const float*)d_in[1];
  const float* mask = (const float*)d_in[2];
  const float* Wq   = (const float*)d_in[3];
  const float* Wk   = (const float*)d_in[4];
  const float* Wv   = (const float*)d_in[5];
  const float* Wo   = (const float*)d_in[6];
  char* ws = (char*)d_ws;
  const size_t MB = (size_t)1 << 20;
  u16* xb  = (u16*)(ws + 0  * MB);     // dead after qkv_gemm
  u16* yb  = (u16*)(ws + 8  * MB);     // dead after qkv_gemm
  u16* wqb = (u16*)(ws + 16 * MB);     // dead after qkv_gemm
  u16* wkb = (u16*)(ws + 18 * MB);
  u16* wvb = (u16*)(ws + 20 * MB);
  u16* wob = (u16*)(ws + 22 * MB);     // needed by out_gemm
  u16* Qw  = (u16*)(ws + 24 * MB);     // [B][H][S][64] bf16, scaled log2e/8
  u16* Kw  = (u16*)(ws + 32 * MB);     // [B][H][S][64] bf16
  u16* Vtw = (u16*)(ws + 40 * MB);     // [B][H][64][S] f16
  u16* Ow  = (u16*)(ws + 48 * MB);     // [B][S][1024] bf16
  u16* maskb = (u16*)(ws + 56 * MB);   // [S][S] bf16, pre-scaled log2e
  // attn-phase overlays on dead regions
  float* Op0  = (float*)(ws + 0 * MB);   // 16 MB over xb+yb
  float* Op1  = (float*)d_out;           // 16 MB; overwritten by out_gemm later
  float* denb = (float*)(ws + 16 * MB);  // 512 KB over wqb

  convert_all<<<16384, 256, 0, stream>>>(x, y, Wq, Wk, Wv, Wo, mask,
                                         xb, yb, wqb, wkb, wvb, wob, maskb);
  qkv_gemm<<<dim3(8, 32, 3), 256, 0, stream>>>(xb, yb, wqb, wkb, wvb, Qw, Kw, Vtw);
  attn_kernel<<<dim3(16, 16, 4), 256, 0, stream>>>(Qw, Kw, Vtw, maskb, Op0, Op1, denb);
  combine<<<4096, 256, 0, stream>>>(Op0, Op1, denb, Ow);
  out_gemm<<<dim3(8, 64), 256, 0, stream>>>(Ow, wob, (float*)d_out);
  (void)in_sizes; (void)n_in; (void)out_size; (void)ws_size;
}